// Round 2
// baseline (1072.800 us; speedup 1.0000x reference)
//
#include <hip/hip_runtime.h>

// ---------------------------------------------------------------------------
// TransformerBlock: B=2,S=2048,D=2048,H=32,HD=64,G=8,KV=256,DFF=5632
// All inputs fp32. Internally bf16 MFMA GEMMs + fp32 softmax/rmsnorm.
// Workspace budget: 190,840,832 bytes (~182 MiB). Residual fp32 lives in d_out.
// ---------------------------------------------------------------------------

typedef __attribute__((ext_vector_type(8))) __bf16 bf16x8;
typedef __attribute__((ext_vector_type(4))) float f32x4;

#define RR 4096      // B*S rows
#define DD 2048
#define KVD 256
#define QKVN 2560    // 2048 q + 256 k + 256 v
#define DFF 5632

// ---------------- workspace layout (bytes) ----------------
static const size_t OFF_WQKV = 0;              // bf16 [2560,2048]  10,485,760
static const size_t OFF_WO   = 10485760;       // bf16 [2048,2048]   8,388,608
static const size_t OFF_WG   = 18874368;       // bf16 [5632,2048]  23,068,672
static const size_t OFF_WU   = 41943040;       // bf16 [5632,2048]  23,068,672
static const size_t OFF_WDN  = 65011712;       // bf16 [2048,5632]  23,068,672
static const size_t OFF_H    = 88080384;       // bf16 [4096,2048]  (h, then attn_out)
static const size_t OFF_QKV  = 104857600;      // bf16 [4096,2560]
static const size_t OFF_Q    = 125829120;      // bf16 [4096,2048]  (q_rope, then h2)
static const size_t OFF_K    = 142606336;      // bf16 [4096,256]
static const size_t OFF_ACT  = 144703488;      // bf16 [4096,5632]  (gate tmp, then silu*up)
static const size_t WS_NEED  = 190840832;

// ---------------- fp32 -> bf16 convert ----------------
__global__ void cvt_kernel(const float* __restrict__ s, __bf16* __restrict__ d, int n4) {
  int i = blockIdx.x * 256 + threadIdx.x;
  if (i >= n4) return;
  float4 v = ((const float4*)s)[i];
  union { __bf16 b[4]; ushort4 u; } c;
  c.b[0] = (__bf16)v.x; c.b[1] = (__bf16)v.y; c.b[2] = (__bf16)v.z; c.b[3] = (__bf16)v.w;
  ((ushort4*)d)[i] = c.u;
}

// ---------------- RMSNorm (row of 2048, 256 threads) ----------------
__global__ __launch_bounds__(256)
void rmsnorm_kernel(const float* __restrict__ x, const float* __restrict__ w,
                    __bf16* __restrict__ out) {
  const int row = blockIdx.x, t = threadIdx.x;
  const float4* xr = (const float4*)(x + (size_t)row * DD);
  float4 a = xr[t], b = xr[t + 256];
  float s = a.x*a.x + a.y*a.y + a.z*a.z + a.w*a.w
          + b.x*b.x + b.y*b.y + b.z*b.z + b.w*b.w;
#pragma unroll
  for (int m = 1; m < 64; m <<= 1) s += __shfl_xor(s, m, 64);
  __shared__ float red[4];
  if ((t & 63) == 0) red[t >> 6] = s;
  __syncthreads();
  float tot = red[0] + red[1] + red[2] + red[3];
  float inv = 1.0f / (sqrtf(tot * (1.0f / 2048.0f) + 1e-6f) + 1e-6f);
  const float4* wr = (const float4*)w;
  float4 w0 = wr[t], w1 = wr[t + 256];
  __bf16* o = out + (size_t)row * DD;
  union { __bf16 bb[4]; ushort4 u; } c;
  c.bb[0] = (__bf16)(a.x*inv*w0.x); c.bb[1] = (__bf16)(a.y*inv*w0.y);
  c.bb[2] = (__bf16)(a.z*inv*w0.z); c.bb[3] = (__bf16)(a.w*inv*w0.w);
  ((ushort4*)o)[t] = c.u;
  c.bb[0] = (__bf16)(b.x*inv*w1.x); c.bb[1] = (__bf16)(b.y*inv*w1.y);
  c.bb[2] = (__bf16)(b.z*inv*w1.z); c.bb[3] = (__bf16)(b.w*inv*w1.w);
  ((ushort4*)o)[t + 256] = c.u;
}

// ---------------- NT GEMM: C[M,N] = A[M,K] * B[N,K]^T ----------------
// 128x128 tile, BK=32, 4 waves each 64x64 (4x4 of 16x16x32 MFMA)
// EPI 0: Cb[idx] = (bf16)acc
// EPI 1: Cf[idx] = Res[idx] + acc               (fp32 residual add)
// EPI 2: Cb[idx] = (bf16)(silu(Cb[idx]) * acc)  (fused SwiGLU; in-place over gate tmp)
template<int EPI>
__global__ __launch_bounds__(256)
void gemm_nt_kernel(const __bf16* __restrict__ A, const __bf16* __restrict__ Bm,
                    __bf16* Cb, const float* __restrict__ Res,
                    float* __restrict__ Cf, int M, int N, int K) {
  __shared__ __align__(16) __bf16 As[128 * 40];
  __shared__ __align__(16) __bf16 Bs[128 * 40];
  const int t = threadIdx.x;
  const int m0 = blockIdx.y * 128, n0 = blockIdx.x * 128;
  const int w = t >> 6, l = t & 63;
  const int wm = w & 1, wn = w >> 1;
  const int lm = l & 15, lq = l >> 4;
  const int sr = t >> 2, sc = t & 3;
  const __bf16* Ab = A + (size_t)(m0 + sr) * K + sc * 8;
  const __bf16* Bb = Bm + (size_t)(n0 + sr) * K + sc * 8;
  f32x4 acc[4][4] = {};
  for (int kt = 0; kt < K; kt += 32) {
    uint4 a0 = *(const uint4*)(Ab + kt);
    uint4 a1 = *(const uint4*)(Ab + (size_t)64 * K + kt);
    uint4 b0 = *(const uint4*)(Bb + kt);
    uint4 b1 = *(const uint4*)(Bb + (size_t)64 * K + kt);
    __syncthreads();
    *(uint4*)&As[sr * 40 + sc * 8] = a0;
    *(uint4*)&As[(sr + 64) * 40 + sc * 8] = a1;
    *(uint4*)&Bs[sr * 40 + sc * 8] = b0;
    *(uint4*)&Bs[(sr + 64) * 40 + sc * 8] = b1;
    __syncthreads();
    bf16x8 af[4], bfr[4];
#pragma unroll
    for (int i = 0; i < 4; i++)
      af[i] = *(const bf16x8*)&As[(wm * 64 + i * 16 + lm) * 40 + lq * 8];
#pragma unroll
    for (int j = 0; j < 4; j++)
      bfr[j] = *(const bf16x8*)&Bs[(wn * 64 + j * 16 + lm) * 40 + lq * 8];
#pragma unroll
    for (int i = 0; i < 4; i++)
#pragma unroll
      for (int j = 0; j < 4; j++)
        acc[i][j] = __builtin_amdgcn_mfma_f32_16x16x32_bf16(af[i], bfr[j], acc[i][j], 0, 0, 0);
  }
#pragma unroll
  for (int i = 0; i < 4; i++)
#pragma unroll
    for (int j = 0; j < 4; j++)
#pragma unroll
      for (int r = 0; r < 4; r++) {
        int row = m0 + wm * 64 + i * 16 + lq * 4 + r;
        int col = n0 + wn * 64 + j * 16 + lm;
        size_t idx = (size_t)row * N + col;
        if (EPI == 0) {
          Cb[idx] = (__bf16)acc[i][j][r];
        } else if (EPI == 1) {
          Cf[idx] = Res[idx] + acc[i][j][r];
        } else {
          float g = (float)Cb[idx];
          Cb[idx] = (__bf16)(g / (1.0f + __expf(-g)) * acc[i][j][r]);
        }
      }
}

// ---------------- rope: out = rot_half(x) * (pm0+pm1) ----------------
__global__ __launch_bounds__(256)
void rope_kernel(const __bf16* __restrict__ qkv, const float* __restrict__ pm,
                 __bf16* __restrict__ qo, __bf16* __restrict__ ko) {
  const int row = blockIdx.x, t = threadIdx.x;
  const int s = row & 2047;
  const __bf16* q = qkv + (size_t)row * QKVN;
  const float* p0 = pm + (size_t)s * DD;
  const float* p1 = p0 + (size_t)2048 * DD;   // pm[1] plane
  __bf16* qr = qo + (size_t)row * DD;
#pragma unroll
  for (int jj = 0; jj < 8; jj++) {
    int i = t + jj * 256;
    float rot = (i < 1024) ? -(float)q[i + 1024] : (float)q[i - 1024];
    qr[i] = (__bf16)(rot * (p0[i] + p1[i]));
  }
  const __bf16* k = q + 2048;
  __bf16* kr = ko + (size_t)row * KVD;
  {
    int i = t;
    float rot = (i < 128) ? -(float)k[i + 128] : (float)k[i - 128];
    kr[i] = (__bf16)(rot * (p0[i] + p1[i]));
  }
}

// ---------------- attention (flash-style; softmax = e/(sum e + 1), no rescale) ----------------
// grid (S/128, H, B). Q tile 128, KV tile 64.
__global__ __launch_bounds__(256)
void attn_kernel(const __bf16* __restrict__ Q, const __bf16* __restrict__ Kb,
                 const __bf16* __restrict__ QKV, __bf16* __restrict__ O) {
  __shared__ __align__(16) __bf16 sQ[128 * 72];
  __shared__ __align__(16) __bf16 sK[64 * 72];
  __shared__ __align__(16) __bf16 sV[64 * 72];   // transposed: [d][k]
  __shared__ __align__(16) __bf16 sE[128 * 72];
  const int t = threadIdx.x, l = t & 63, w = t >> 6;
  const int lm = l & 15, lq = l >> 4;
  const int q0 = blockIdx.x * 128;
  const int h = blockIdx.y, b = blockIdx.z;
  const int p = h & 3;                 // kv slice: head h uses dims p*64..p*64+64
  const float scale = 1.0f / (16.0f + 1e-6f);
  {
    // 128 rows x 64 cols: 4 uint4 per thread
    const int qr = t >> 3, qc = (t & 7) * 8;
#pragma unroll
    for (int it = 0; it < 4; it++) {
      size_t base = ((size_t)(b * 2048 + q0 + qr + it * 32)) * DD + h * 64 + qc;
      *(uint4*)&sQ[(qr + it * 32) * 72 + qc] = *(const uint4*)(Q + base);
    }
  }
  f32x4 oacc[2][4] = {};
  float denom[2][4] = {{0,0,0,0},{0,0,0,0}};
  const int ksr = t >> 2, ksc = (t & 3) * 16;   // K: 64 rows x 64 cols, 2 uint4/thread
  const int vr = t >> 3, vc = t & 7;
  for (int kt = 0; kt < 2048; kt += 64) {
    const __bf16* krow = Kb + ((size_t)(b * 2048 + kt + ksr)) * KVD + p * 64 + ksc;
    uint4 kv0 = *(const uint4*)(krow);
    uint4 kv1 = *(const uint4*)(krow + 8);
    uint4 vv0 = *(const uint4*)(QKV + ((size_t)(b * 2048 + kt + vr)) * QKVN + 2304 + p * 64 + vc * 8);
    uint4 vv1 = *(const uint4*)(QKV + ((size_t)(b * 2048 + kt + vr + 32)) * QKVN + 2304 + p * 64 + vc * 8);
    __syncthreads();                       // prev iter's LDS consumers done
    *(uint4*)&sK[ksr * 72 + ksc] = kv0;
    *(uint4*)&sK[ksr * 72 + ksc + 8] = kv1;
    {
      const __bf16* pv0 = (const __bf16*)&vv0;
      const __bf16* pv1 = (const __bf16*)&vv1;
#pragma unroll
      for (int j2 = 0; j2 < 8; j2++) {
        sV[(vc * 8 + j2) * 72 + vr] = pv0[j2];
        sV[(vc * 8 + j2) * 72 + vr + 32] = pv1[j2];
      }
    }
    __syncthreads();
    // ---- S = Q K^T ----
    f32x4 sacc[2][4] = {};
#pragma unroll
    for (int kk = 0; kk < 2; kk++) {
      bf16x8 aq[2], bk[4];
#pragma unroll
      for (int i = 0; i < 2; i++) aq[i] = *(const bf16x8*)&sQ[(w * 32 + i * 16 + lm) * 72 + kk * 32 + lq * 8];
#pragma unroll
      for (int j = 0; j < 4; j++) bk[j] = *(const bf16x8*)&sK[(j * 16 + lm) * 72 + kk * 32 + lq * 8];
#pragma unroll
      for (int i = 0; i < 2; i++)
#pragma unroll
        for (int j = 0; j < 4; j++)
          sacc[i][j] = __builtin_amdgcn_mfma_f32_16x16x32_bf16(aq[i], bk[j], sacc[i][j], 0, 0, 0);
    }
    // ---- exp, denominator, E tile (own-wave rows only) ----
#pragma unroll
    for (int i = 0; i < 2; i++) {
      float tmp[4] = {0, 0, 0, 0};
#pragma unroll
      for (int j = 0; j < 4; j++)
#pragma unroll
        for (int r = 0; r < 4; r++) {
          float e = __expf(sacc[i][j][r] * scale);
          tmp[r] += e;
          sE[(w * 32 + i * 16 + lq * 4 + r) * 72 + j * 16 + lm] = (__bf16)e;
        }
#pragma unroll
      for (int m = 1; m < 16; m <<= 1)
#pragma unroll
        for (int r = 0; r < 4; r++) tmp[r] += __shfl_xor(tmp[r], m, 64);
#pragma unroll
      for (int r = 0; r < 4; r++) denom[i][r] += tmp[r];
    }
    // ---- O += E V  (E rows are own-wave; sV synced above) ----
#pragma unroll
    for (int ks = 0; ks < 2; ks++) {
      bf16x8 ae[2], bv[4];
#pragma unroll
      for (int i = 0; i < 2; i++) ae[i] = *(const bf16x8*)&sE[(w * 32 + i * 16 + lm) * 72 + ks * 32 + lq * 8];
#pragma unroll
      for (int j = 0; j < 4; j++) bv[j] = *(const bf16x8*)&sV[(j * 16 + lm) * 72 + ks * 32 + lq * 8];
#pragma unroll
      for (int i = 0; i < 2; i++)
#pragma unroll
        for (int j = 0; j < 4; j++)
          oacc[i][j] = __builtin_amdgcn_mfma_f32_16x16x32_bf16(ae[i], bv[j], oacc[i][j], 0, 0, 0);
    }
  }
#pragma unroll
  for (int i = 0; i < 2; i++)
#pragma unroll
    for (int j = 0; j < 4; j++)
#pragma unroll
      for (int r = 0; r < 4; r++) {
        int row = q0 + w * 32 + i * 16 + lq * 4 + r;
        int col = h * 64 + j * 16 + lm;
        O[((size_t)(b * 2048 + row)) * DD + col] = (__bf16)(oacc[i][j][r] / (denom[i][r] + 1.0f));
      }
}

// ---------------------------------------------------------------------------
extern "C" void kernel_launch(void* const* d_in, const int* in_sizes, int n_in,
                              void* d_out, int out_size, void* d_ws, size_t ws_size,
                              hipStream_t stream) {
  if (ws_size < WS_NEED) return;   // diagnostic guard: undersized scratch -> clean fail, not fault

  const float* x    = (const float*)d_in[0];
  const float* pm   = (const float*)d_in[1];
  const float* w_na = (const float*)d_in[2];
  const float* w_nf = (const float*)d_in[3];
  const float* wq   = (const float*)d_in[4];
  const float* wk   = (const float*)d_in[5];
  const float* wv   = (const float*)d_in[6];
  const float* wo   = (const float*)d_in[7];
  const float* wg   = (const float*)d_in[8];
  const float* wu   = (const float*)d_in[9];
  const float* wd   = (const float*)d_in[10];

  char* ws = (char*)d_ws;
  __bf16* wqkv_b = (__bf16*)(ws + OFF_WQKV);
  __bf16* wo_b   = (__bf16*)(ws + OFF_WO);
  __bf16* wg_b   = (__bf16*)(ws + OFF_WG);
  __bf16* wu_b   = (__bf16*)(ws + OFF_WU);
  __bf16* wdn_b  = (__bf16*)(ws + OFF_WDN);
  __bf16* h_b    = (__bf16*)(ws + OFF_H);
  __bf16* qkv_b  = (__bf16*)(ws + OFF_QKV);
  __bf16* q_b    = (__bf16*)(ws + OFF_Q);
  __bf16* k_b    = (__bf16*)(ws + OFF_K);
  __bf16* act_b  = (__bf16*)(ws + OFF_ACT);
  float*  x1     = (float*)d_out;   // residual accumulator lives in d_out

  // weight conversions (fp32 -> bf16)
  cvt_kernel<<<4096, 256, 0, stream>>>(wq, wqkv_b, 1048576);
  cvt_kernel<<<512, 256, 0, stream>>>(wk, wqkv_b + (size_t)2048 * 2048, 131072);
  cvt_kernel<<<512, 256, 0, stream>>>(wv, wqkv_b + (size_t)2304 * 2048, 131072);
  cvt_kernel<<<4096, 256, 0, stream>>>(wo, wo_b, 1048576);
  cvt_kernel<<<11264, 256, 0, stream>>>(wg, wg_b, 2883584);
  cvt_kernel<<<11264, 256, 0, stream>>>(wu, wu_b, 2883584);
  cvt_kernel<<<11264, 256, 0, stream>>>(wd, wdn_b, 2883584);

  // ---- attention sublayer ----
  rmsnorm_kernel<<<4096, 256, 0, stream>>>(x, w_na, h_b);
  gemm_nt_kernel<0><<<dim3(20, 32), 256, 0, stream>>>(h_b, wqkv_b, qkv_b, nullptr, nullptr,
                                                      RR, QKVN, DD);
  rope_kernel<<<4096, 256, 0, stream>>>(qkv_b, pm, q_b, k_b);
  attn_kernel<<<dim3(16, 32, 2), 256, 0, stream>>>(q_b, k_b, qkv_b, h_b);
  gemm_nt_kernel<1><<<dim3(16, 32), 256, 0, stream>>>(h_b, wo_b, nullptr, x, x1,
                                                      RR, DD, DD);
  // ---- feedforward sublayer ----
  rmsnorm_kernel<<<4096, 256, 0, stream>>>(x1, w_nf, q_b);
  gemm_nt_kernel<0><<<dim3(44, 32), 256, 0, stream>>>(q_b, wg_b, act_b, nullptr, nullptr,
                                                      RR, DFF, DD);
  gemm_nt_kernel<2><<<dim3(44, 32), 256, 0, stream>>>(q_b, wu_b, act_b, nullptr, nullptr,
                                                      RR, DFF, DD);
  gemm_nt_kernel<1><<<dim3(16, 32), 256, 0, stream>>>(act_b, wdn_b, nullptr, x1, x1,
                                                      RR, DD, DFF);
}

// Round 3
// 1024.555 us; speedup vs baseline: 1.0471x; 1.0471x over previous
//
#include <hip/hip_runtime.h>

// ---------------------------------------------------------------------------
// TransformerBlock: B=2,S=2048,D=2048,H=32,HD=64,G=8,KV=256,DFF=5632
// fp32 in/out. Internally bf16 MFMA GEMMs (m97-style global_load_lds staging)
// + fp32 softmax/rmsnorm. Residual fp32 lives in d_out.
// ---------------------------------------------------------------------------

typedef __attribute__((ext_vector_type(8))) __bf16 bf16x8;
typedef __attribute__((ext_vector_type(4))) float f32x4;

#define RR 4096      // B*S rows
#define DD 2048
#define KVD 256
#define QKVN 2560    // 2048 q + 256 k + 256 v
#define DFF 5632

// ---------------- workspace layout (bytes) ----------------
static const size_t OFF_WQKV = 0;              // bf16 [2560,2048]
static const size_t OFF_WO   = 10485760;       // bf16 [2048,2048]
static const size_t OFF_WG   = 18874368;       // bf16 [5632,2048]
static const size_t OFF_WU   = 41943040;       // bf16 [5632,2048]
static const size_t OFF_WDN  = 65011712;       // bf16 [2048,5632]
static const size_t OFF_H    = 88080384;       // bf16 [4096,2048]  (h, then attn_out)
static const size_t OFF_QKV  = 104857600;      // bf16 [4096,2560]
static const size_t OFF_Q    = 125829120;      // bf16 [4096,2048]  (q_rope, then h2)
static const size_t OFF_K    = 142606336;      // bf16 [4096,256]
static const size_t OFF_ACT  = 144703488;      // bf16 [4096,5632]  (gate tmp, then silu*up)
static const size_t WS_NEED  = 190840832;

// ---------------- async global->LDS 16B ----------------
__device__ __forceinline__ void glds16(const __bf16* g, __bf16* s) {
  __builtin_amdgcn_global_load_lds(
      (const __attribute__((address_space(1))) unsigned int*)(const void*)g,
      (__attribute__((address_space(3))) unsigned int*)(void*)s, 16, 0, 0);
}

// ---------------- fp32 -> bf16 convert ----------------
__global__ void cvt_kernel(const float* __restrict__ s, __bf16* __restrict__ d, int n4) {
  int i = blockIdx.x * 256 + threadIdx.x;
  if (i >= n4) return;
  float4 v = ((const float4*)s)[i];
  union { __bf16 b[4]; ushort4 u; } c;
  c.b[0] = (__bf16)v.x; c.b[1] = (__bf16)v.y; c.b[2] = (__bf16)v.z; c.b[3] = (__bf16)v.w;
  ((ushort4*)d)[i] = c.u;
}

// ---------------- RMSNorm (row of 2048, 256 threads) ----------------
__global__ __launch_bounds__(256)
void rmsnorm_kernel(const float* __restrict__ x, const float* __restrict__ w,
                    __bf16* __restrict__ out) {
  const int row = blockIdx.x, t = threadIdx.x;
  const float4* xr = (const float4*)(x + (size_t)row * DD);
  float4 a = xr[t], b = xr[t + 256];
  float s = a.x*a.x + a.y*a.y + a.z*a.z + a.w*a.w
          + b.x*b.x + b.y*b.y + b.z*b.z + b.w*b.w;
#pragma unroll
  for (int m = 1; m < 64; m <<= 1) s += __shfl_xor(s, m, 64);
  __shared__ float red[4];
  if ((t & 63) == 0) red[t >> 6] = s;
  __syncthreads();
  float tot = red[0] + red[1] + red[2] + red[3];
  float inv = 1.0f / (sqrtf(tot * (1.0f / 2048.0f) + 1e-6f) + 1e-6f);
  const float4* wr = (const float4*)w;
  float4 w0 = wr[t], w1 = wr[t + 256];
  __bf16* o = out + (size_t)row * DD;
  union { __bf16 bb[4]; ushort4 u; } c;
  c.bb[0] = (__bf16)(a.x*inv*w0.x); c.bb[1] = (__bf16)(a.y*inv*w0.y);
  c.bb[2] = (__bf16)(a.z*inv*w0.z); c.bb[3] = (__bf16)(a.w*inv*w0.w);
  ((ushort4*)o)[t] = c.u;
  c.bb[0] = (__bf16)(b.x*inv*w1.x); c.bb[1] = (__bf16)(b.y*inv*w1.y);
  c.bb[2] = (__bf16)(b.z*inv*w1.z); c.bb[3] = (__bf16)(b.w*inv*w1.w);
  ((ushort4*)o)[t + 256] = c.u;
}

// ---------------- NT GEMM: C[M,N] = A[M,K] * B[N,K]^T ----------------
// 128x128 tile, BK=32, m97-style global_load_lds(16B) staging with XOR atom
// swizzle (atom' = atom ^ ((row>>1)&3)) applied at the global source so the
// lane-ordered LDS destination still reconstructs the swizzled layout.
// EPI 0: Cb = (bf16)acc
// EPI 1: Cf = Res + acc                       (fp32 residual add)
// EPI 2: Cb = (bf16)(silu(Cb) * acc)          (fused SwiGLU, in place)
template<int EPI>
__global__ __launch_bounds__(256)
void gemm_nt_kernel(const __bf16* __restrict__ A, const __bf16* __restrict__ Bm,
                    __bf16* Cb, const float* __restrict__ Res,
                    float* __restrict__ Cf, int M, int N, int K) {
  __shared__ __align__(16) __bf16 As[128 * 32];
  __shared__ __align__(16) __bf16 Bs[128 * 32];
  const int t = threadIdx.x;
  const int m0 = blockIdx.y * 128, n0 = blockIdx.x * 128;
  const int w = t >> 6, l = t & 63;
  const int wm = w & 1, wn = w >> 1;
  const int lm = l & 15, lq = l >> 4;
  // staging: slot = issue*256 + w*64 + l ; row = slot>>2 ; aphys = slot&3
  const int slot = w * 64 + l;
  const int r0 = slot >> 2;               // issue 0 row (0..63); issue 1 = r0+64
  const int a0 = (slot & 3) ^ ((r0 >> 1) & 3);   // same for issue 1 (row+64 keeps (row>>1)&3)
  const __bf16* Ap0 = A + (size_t)(m0 + r0) * K + a0 * 8;
  const __bf16* Ap1 = A + (size_t)(m0 + r0 + 64) * K + a0 * 8;
  const __bf16* Bp0 = Bm + (size_t)(n0 + r0) * K + a0 * 8;
  const __bf16* Bp1 = Bm + (size_t)(n0 + r0 + 64) * K + a0 * 8;
  __bf16* AsW0 = As + w * 512;            // wave-uniform LDS bases (atoms*8)
  __bf16* AsW1 = As + 2048 + w * 512;
  __bf16* BsW0 = Bs + w * 512;
  __bf16* BsW1 = Bs + 2048 + w * 512;
  // fragment-read swizzle term
  const int sw = (lm >> 1) & 3;
  f32x4 acc[4][4] = {};
  for (int kt = 0; kt < K; kt += 32) {
    __syncthreads();                      // prior-iter LDS reads done
    glds16(Ap0 + kt, AsW0);
    glds16(Ap1 + kt, AsW1);
    glds16(Bp0 + kt, BsW0);
    glds16(Bp1 + kt, BsW1);
    __syncthreads();                      // drains vmcnt -> tiles in LDS
    bf16x8 af[4], bfr[4];
#pragma unroll
    for (int i = 0; i < 4; i++)
      af[i] = *(const bf16x8*)&As[(wm * 64 + i * 16 + lm) * 32 + (lq ^ sw) * 8];
#pragma unroll
    for (int j = 0; j < 4; j++)
      bfr[j] = *(const bf16x8*)&Bs[(wn * 64 + j * 16 + lm) * 32 + (lq ^ sw) * 8];
#pragma unroll
    for (int i = 0; i < 4; i++)
#pragma unroll
      for (int j = 0; j < 4; j++)
        acc[i][j] = __builtin_amdgcn_mfma_f32_16x16x32_bf16(af[i], bfr[j], acc[i][j], 0, 0, 0);
  }
#pragma unroll
  for (int i = 0; i < 4; i++)
#pragma unroll
    for (int j = 0; j < 4; j++)
#pragma unroll
      for (int r = 0; r < 4; r++) {
        int row = m0 + wm * 64 + i * 16 + lq * 4 + r;
        int col = n0 + wn * 64 + j * 16 + lm;
        size_t idx = (size_t)row * N + col;
        if (EPI == 0) {
          Cb[idx] = (__bf16)acc[i][j][r];
        } else if (EPI == 1) {
          Cf[idx] = Res[idx] + acc[i][j][r];
        } else {
          float g = (float)Cb[idx];
          Cb[idx] = (__bf16)(g / (1.0f + __expf(-g)) * acc[i][j][r]);
        }
      }
}

// ---------------- rope: out = rot_half(x) * (pm0+pm1) ----------------
__global__ __launch_bounds__(256)
void rope_kernel(const __bf16* __restrict__ qkv, const float* __restrict__ pm,
                 __bf16* __restrict__ qo, __bf16* __restrict__ ko) {
  const int row = blockIdx.x, t = threadIdx.x;
  const int s = row & 2047;
  const __bf16* q = qkv + (size_t)row * QKVN;
  const float* p0 = pm + (size_t)s * DD;
  const float* p1 = p0 + (size_t)2048 * DD;
  __bf16* qr = qo + (size_t)row * DD;
#pragma unroll
  for (int jj = 0; jj < 8; jj++) {
    int i = t + jj * 256;
    float rot = (i < 1024) ? -(float)q[i + 1024] : (float)q[i - 1024];
    qr[i] = (__bf16)(rot * (p0[i] + p1[i]));
  }
  const __bf16* k = q + 2048;
  __bf16* kr = ko + (size_t)row * KVD;
  {
    int i = t;
    float rot = (i < 128) ? -(float)k[i + 128] : (float)k[i - 128];
    kr[i] = (__bf16)(rot * (p0[i] + p1[i]));
  }
}

// ---------------- attention (flash-style; softmax = e/(sum e + 1)) ----------------
// grid (S/128, H, B). Q tile 128, KV tile 64.
__global__ __launch_bounds__(256)
void attn_kernel(const __bf16* __restrict__ Q, const __bf16* __restrict__ Kb,
                 const __bf16* __restrict__ QKV, __bf16* __restrict__ O) {
  __shared__ __align__(16) __bf16 sQ[128 * 72];
  __shared__ __align__(16) __bf16 sK[64 * 72];
  __shared__ __align__(16) __bf16 sV[64 * 72];   // [d][k] (V^T)
  __shared__ __align__(16) __bf16 sE[128 * 72];
  const int t = threadIdx.x, l = t & 63, w = t >> 6;
  const int lm = l & 15, lq = l >> 4;
  const int q0 = blockIdx.x * 128;
  const int h = blockIdx.y, b = blockIdx.z;
  const int p = h & 3;                 // kv slice: head h uses dims p*64..p*64+64
  const float scale = 1.0f / (16.0f + 1e-6f);
  {
    const int qr = t >> 3, qc = (t & 7) * 8;
#pragma unroll
    for (int it = 0; it < 4; it++) {
      size_t base = ((size_t)(b * 2048 + q0 + qr + it * 32)) * DD + h * 64 + qc;
      *(uint4*)&sQ[(qr + it * 32) * 72 + qc] = *(const uint4*)(Q + base);
    }
  }
  f32x4 oacc[2][4] = {};
  float denom[2][4] = {{0,0,0,0},{0,0,0,0}};
  const int ksr = t >> 2, ksc = (t & 3) * 16;   // K: 64 rows x 64 cols, 2 uint4/thread
  for (int kt = 0; kt < 2048; kt += 64) {
    const __bf16* krow = Kb + ((size_t)(b * 2048 + kt + ksr)) * KVD + p * 64 + ksc;
    uint4 kv0 = *(const uint4*)(krow);
    uint4 kv1 = *(const uint4*)(krow + 8);
    // V column-mode: lane = d (coalesced 128B/instr), wave w covers k = w*16..+15
    unsigned int vpack[8];
    {
      const __bf16* vbase = QKV + ((size_t)(b * 2048 + kt + w * 16)) * QKVN + 2304 + p * 64 + l;
#pragma unroll
      for (int j2 = 0; j2 < 8; j2++) {
        unsigned int u0 = *(const unsigned short*)(vbase + (size_t)(2 * j2) * QKVN);
        unsigned int u1 = *(const unsigned short*)(vbase + (size_t)(2 * j2 + 1) * QKVN);
        vpack[j2] = u0 | (u1 << 16);
      }
    }
    __syncthreads();                       // prev iter's LDS consumers done
    *(uint4*)&sK[ksr * 72 + ksc] = kv0;
    *(uint4*)&sK[ksr * 72 + ksc + 8] = kv1;
    *(uint4*)&sV[l * 72 + w * 16] = *(uint4*)&vpack[0];
    *(uint4*)&sV[l * 72 + w * 16 + 8] = *(uint4*)&vpack[4];
    __syncthreads();
    // ---- S = Q K^T ----
    f32x4 sacc[2][4] = {};
#pragma unroll
    for (int kk = 0; kk < 2; kk++) {
      bf16x8 aq[2], bk[4];
#pragma unroll
      for (int i = 0; i < 2; i++) aq[i] = *(const bf16x8*)&sQ[(w * 32 + i * 16 + lm) * 72 + kk * 32 + lq * 8];
#pragma unroll
      for (int j = 0; j < 4; j++) bk[j] = *(const bf16x8*)&sK[(j * 16 + lm) * 72 + kk * 32 + lq * 8];
#pragma unroll
      for (int i = 0; i < 2; i++)
#pragma unroll
        for (int j = 0; j < 4; j++)
          sacc[i][j] = __builtin_amdgcn_mfma_f32_16x16x32_bf16(aq[i], bk[j], sacc[i][j], 0, 0, 0);
    }
    // ---- exp, denominator, E tile (own-wave rows only) ----
#pragma unroll
    for (int i = 0; i < 2; i++) {
      float tmp[4] = {0, 0, 0, 0};
#pragma unroll
      for (int j = 0; j < 4; j++)
#pragma unroll
        for (int r = 0; r < 4; r++) {
          float e = __expf(sacc[i][j][r] * scale);
          tmp[r] += e;
          sE[(w * 32 + i * 16 + lq * 4 + r) * 72 + j * 16 + lm] = (__bf16)e;
        }
#pragma unroll
      for (int m = 1; m < 16; m <<= 1)
#pragma unroll
        for (int r = 0; r < 4; r++) tmp[r] += __shfl_xor(tmp[r], m, 64);
#pragma unroll
      for (int r = 0; r < 4; r++) denom[i][r] += tmp[r];
    }
    // ---- O += E V ----
#pragma unroll
    for (int ks = 0; ks < 2; ks++) {
      bf16x8 ae[2], bv[4];
#pragma unroll
      for (int i = 0; i < 2; i++) ae[i] = *(const bf16x8*)&sE[(w * 32 + i * 16 + lm) * 72 + ks * 32 + lq * 8];
#pragma unroll
      for (int j = 0; j < 4; j++) bv[j] = *(const bf16x8*)&sV[(j * 16 + lm) * 72 + ks * 32 + lq * 8];
#pragma unroll
      for (int i = 0; i < 2; i++)
#pragma unroll
        for (int j = 0; j < 4; j++)
          oacc[i][j] = __builtin_amdgcn_mfma_f32_16x16x32_bf16(ae[i], bv[j], oacc[i][j], 0, 0, 0);
    }
  }
#pragma unroll
  for (int i = 0; i < 2; i++)
#pragma unroll
    for (int j = 0; j < 4; j++)
#pragma unroll
      for (int r = 0; r < 4; r++) {
        int row = q0 + w * 32 + i * 16 + lq * 4 + r;
        int col = h * 64 + j * 16 + lm;
        O[((size_t)(b * 2048 + row)) * DD + col] = (__bf16)(oacc[i][j][r] / (denom[i][r] + 1.0f));
      }
}

// ---------------------------------------------------------------------------
extern "C" void kernel_launch(void* const* d_in, const int* in_sizes, int n_in,
                              void* d_out, int out_size, void* d_ws, size_t ws_size,
                              hipStream_t stream) {
  if (ws_size < WS_NEED) return;

  const float* x    = (const float*)d_in[0];
  const float* pm   = (const float*)d_in[1];
  const float* w_na = (const float*)d_in[2];
  const float* w_nf = (const float*)d_in[3];
  const float* wq   = (const float*)d_in[4];
  const float* wk   = (const float*)d_in[5];
  const float* wv   = (const float*)d_in[6];
  const float* wo   = (const float*)d_in[7];
  const float* wg   = (const float*)d_in[8];
  const float* wu   = (const float*)d_in[9];
  const float* wd   = (const float*)d_in[10];

  char* ws = (char*)d_ws;
  __bf16* wqkv_b = (__bf16*)(ws + OFF_WQKV);
  __bf16* wo_b   = (__bf16*)(ws + OFF_WO);
  __bf16* wg_b   = (__bf16*)(ws + OFF_WG);
  __bf16* wu_b   = (__bf16*)(ws + OFF_WU);
  __bf16* wdn_b  = (__bf16*)(ws + OFF_WDN);
  __bf16* h_b    = (__bf16*)(ws + OFF_H);
  __bf16* qkv_b  = (__bf16*)(ws + OFF_QKV);
  __bf16* q_b    = (__bf16*)(ws + OFF_Q);
  __bf16* k_b    = (__bf16*)(ws + OFF_K);
  __bf16* act_b  = (__bf16*)(ws + OFF_ACT);
  float*  x1     = (float*)d_out;

  cvt_kernel<<<4096, 256, 0, stream>>>(wq, wqkv_b, 1048576);
  cvt_kernel<<<512, 256, 0, stream>>>(wk, wqkv_b + (size_t)2048 * 2048, 131072);
  cvt_kernel<<<512, 256, 0, stream>>>(wv, wqkv_b + (size_t)2304 * 2048, 131072);
  cvt_kernel<<<4096, 256, 0, stream>>>(wo, wo_b, 1048576);
  cvt_kernel<<<11264, 256, 0, stream>>>(wg, wg_b, 2883584);
  cvt_kernel<<<11264, 256, 0, stream>>>(wu, wu_b, 2883584);
  cvt_kernel<<<11264, 256, 0, stream>>>(wd, wdn_b, 2883584);

  // ---- attention sublayer ----
  rmsnorm_kernel<<<4096, 256, 0, stream>>>(x, w_na, h_b);
  gemm_nt_kernel<0><<<dim3(20, 32), 256, 0, stream>>>(h_b, wqkv_b, qkv_b, nullptr, nullptr,
                                                      RR, QKVN, DD);
  rope_kernel<<<4096, 256, 0, stream>>>(qkv_b, pm, q_b, k_b);
  attn_kernel<<<dim3(16, 32, 2), 256, 0, stream>>>(q_b, k_b, qkv_b, h_b);
  gemm_nt_kernel<1><<<dim3(16, 32), 256, 0, stream>>>(h_b, wo_b, nullptr, x, x1,
                                                      RR, DD, DD);
  // ---- feedforward sublayer ----
  rmsnorm_kernel<<<4096, 256, 0, stream>>>(x1, w_nf, q_b);
  gemm_nt_kernel<0><<<dim3(44, 32), 256, 0, stream>>>(q_b, wg_b, act_b, nullptr, nullptr,
                                                      RR, DFF, DD);
  gemm_nt_kernel<2><<<dim3(44, 32), 256, 0, stream>>>(q_b, wu_b, act_b, nullptr, nullptr,
                                                      RR, DFF, DD);
  gemm_nt_kernel<1><<<dim3(16, 32), 256, 0, stream>>>(act_b, wdn_b, nullptr, x1, x1,
                                                      RR, DD, DFF);
}

// Round 4
// 988.353 us; speedup vs baseline: 1.0854x; 1.0366x over previous
//
#include <hip/hip_runtime.h>

// ---------------------------------------------------------------------------
// TransformerBlock: B=2,S=2048,D=2048,H=32,HD=64,G=8,KV=256,DFF=5632
// fp32 in/out. bf16 MFMA GEMMs (global_load_lds staging + XCD-locality block
// swizzle) + transposed-S flash attention (no P round-trip through LDS).
// ---------------------------------------------------------------------------

typedef __attribute__((ext_vector_type(8))) __bf16 bf16x8;
typedef __attribute__((ext_vector_type(4))) __bf16 bf16x4;
typedef __attribute__((ext_vector_type(4))) float f32x4;

#define RR 4096      // B*S rows
#define DD 2048
#define KVD 256
#define QKVN 2560    // 2048 q + 256 k + 256 v
#define DFF 5632

// ---------------- workspace layout (bytes) ----------------
static const size_t OFF_WQKV = 0;              // bf16 [2560,2048]
static const size_t OFF_WO   = 10485760;       // bf16 [2048,2048]
static const size_t OFF_WG   = 18874368;       // bf16 [5632,2048]
static const size_t OFF_WU   = 41943040;       // bf16 [5632,2048]
static const size_t OFF_WDN  = 65011712;       // bf16 [2048,5632]
static const size_t OFF_H    = 88080384;       // bf16 [4096,2048]  (h, then attn_out)
static const size_t OFF_QKV  = 104857600;      // bf16 [4096,2560]
static const size_t OFF_Q    = 125829120;      // bf16 [4096,2048]  (q_rope, then h2)
static const size_t OFF_K    = 142606336;      // bf16 [4096,256]
static const size_t OFF_ACT  = 144703488;      // bf16 [4096,5632]  (gate tmp, then silu*up)
static const size_t WS_NEED  = 190840832;

// ---------------- async global->LDS 16B ----------------
__device__ __forceinline__ void glds16(const __bf16* g, __bf16* s) {
  __builtin_amdgcn_global_load_lds(
      (const __attribute__((address_space(1))) unsigned int*)(const void*)g,
      (__attribute__((address_space(3))) unsigned int*)(void*)s, 16, 0, 0);
}

// ---------------- fp32 -> bf16 convert ----------------
__global__ void cvt_kernel(const float* __restrict__ s, __bf16* __restrict__ d, int n4) {
  int i = blockIdx.x * 256 + threadIdx.x;
  if (i >= n4) return;
  float4 v = ((const float4*)s)[i];
  union { __bf16 b[4]; ushort4 u; } c;
  c.b[0] = (__bf16)v.x; c.b[1] = (__bf16)v.y; c.b[2] = (__bf16)v.z; c.b[3] = (__bf16)v.w;
  ((ushort4*)d)[i] = c.u;
}

// ---------------- RMSNorm (row of 2048, 256 threads) ----------------
__global__ __launch_bounds__(256)
void rmsnorm_kernel(const float* __restrict__ x, const float* __restrict__ w,
                    __bf16* __restrict__ out) {
  const int row = blockIdx.x, t = threadIdx.x;
  const float4* xr = (const float4*)(x + (size_t)row * DD);
  float4 a = xr[t], b = xr[t + 256];
  float s = a.x*a.x + a.y*a.y + a.z*a.z + a.w*a.w
          + b.x*b.x + b.y*b.y + b.z*b.z + b.w*b.w;
#pragma unroll
  for (int m = 1; m < 64; m <<= 1) s += __shfl_xor(s, m, 64);
  __shared__ float red[4];
  if ((t & 63) == 0) red[t >> 6] = s;
  __syncthreads();
  float tot = red[0] + red[1] + red[2] + red[3];
  float inv = 1.0f / (sqrtf(tot * (1.0f / 2048.0f) + 1e-6f) + 1e-6f);
  const float4* wr = (const float4*)w;
  float4 w0 = wr[t], w1 = wr[t + 256];
  __bf16* o = out + (size_t)row * DD;
  union { __bf16 bb[4]; ushort4 u; } c;
  c.bb[0] = (__bf16)(a.x*inv*w0.x); c.bb[1] = (__bf16)(a.y*inv*w0.y);
  c.bb[2] = (__bf16)(a.z*inv*w0.z); c.bb[3] = (__bf16)(a.w*inv*w0.w);
  ((ushort4*)o)[t] = c.u;
  c.bb[0] = (__bf16)(b.x*inv*w1.x); c.bb[1] = (__bf16)(b.y*inv*w1.y);
  c.bb[2] = (__bf16)(b.z*inv*w1.z); c.bb[3] = (__bf16)(b.w*inv*w1.w);
  ((ushort4*)o)[t + 256] = c.u;
}

// ---------------- NT GEMM: C[M,N] = A[M,K] * B[N,K]^T ----------------
// 128x128 tile, BK=32, global_load_lds(16B) staging.
// Block swizzle: XCD (lid&7) owns m-band [xcd*4 .. xcd*4+3]; n walked in
// 4-strip chunks so each B-strip's 4 m-uses land in one 16-block window (L2-hot).
// EPI 0: Cb=(bf16)acc; EPI 1: Cf=Res+acc; EPI 2: Cb=(bf16)(silu(Cb)*acc)
template<int EPI>
__global__ __launch_bounds__(256)
void gemm_nt_kernel(const __bf16* __restrict__ A, const __bf16* __restrict__ Bm,
                    __bf16* Cb, const float* __restrict__ Res,
                    float* __restrict__ Cf, int M, int N, int K) {
  __shared__ __align__(16) __bf16 As[128 * 32];
  __shared__ __align__(16) __bf16 Bs[128 * 32];
  const int t = threadIdx.x;
  const int GM = M >> 7, GN = N >> 7;
  int m_t, n_t;
  if (GM == 32 && (GN & 3) == 0) {
    int lid = blockIdx.y * gridDim.x + blockIdx.x;
    int xcd = lid & 7, i = lid >> 3;
    int c = i >> 4, j = i & 15;
    m_t = xcd * 4 + (j & 3);
    n_t = c * 4 + (j >> 2);
  } else {
    m_t = blockIdx.y; n_t = blockIdx.x;
  }
  const int m0 = m_t * 128, n0 = n_t * 128;
  const int w = t >> 6, l = t & 63;
  const int wm = w & 1, wn = w >> 1;
  const int lm = l & 15, lq = l >> 4;
  // staging: slot = w*64 + l ; row = slot>>2 ; atom = slot&3
  const int slot = w * 64 + l;
  const int r0 = slot >> 2;
  const int a0 = slot & 3;
  const __bf16* Ap0 = A + (size_t)(m0 + r0) * K + a0 * 8;
  const __bf16* Ap1 = A + (size_t)(m0 + r0 + 64) * K + a0 * 8;
  const __bf16* Bp0 = Bm + (size_t)(n0 + r0) * K + a0 * 8;
  const __bf16* Bp1 = Bm + (size_t)(n0 + r0 + 64) * K + a0 * 8;
  __bf16* AsW0 = As + w * 512;            // wave-uniform LDS bases
  __bf16* AsW1 = As + 2048 + w * 512;
  __bf16* BsW0 = Bs + w * 512;
  __bf16* BsW1 = Bs + 2048 + w * 512;
  f32x4 acc[4][4] = {};
  for (int kt = 0; kt < K; kt += 32) {
    __syncthreads();
    glds16(Ap0 + kt, AsW0);
    glds16(Ap1 + kt, AsW1);
    glds16(Bp0 + kt, BsW0);
    glds16(Bp1 + kt, BsW1);
    __syncthreads();
    bf16x8 af[4], bfr[4];
#pragma unroll
    for (int i = 0; i < 4; i++)
      af[i] = *(const bf16x8*)&As[(wm * 64 + i * 16 + lm) * 32 + lq * 8];
#pragma unroll
    for (int j = 0; j < 4; j++)
      bfr[j] = *(const bf16x8*)&Bs[(wn * 64 + j * 16 + lm) * 32 + lq * 8];
#pragma unroll
    for (int i = 0; i < 4; i++)
#pragma unroll
      for (int j = 0; j < 4; j++)
        acc[i][j] = __builtin_amdgcn_mfma_f32_16x16x32_bf16(af[i], bfr[j], acc[i][j], 0, 0, 0);
  }
#pragma unroll
  for (int i = 0; i < 4; i++)
#pragma unroll
    for (int j = 0; j < 4; j++)
#pragma unroll
      for (int r = 0; r < 4; r++) {
        int row = m0 + wm * 64 + i * 16 + lq * 4 + r;
        int col = n0 + wn * 64 + j * 16 + lm;
        size_t idx = (size_t)row * N + col;
        if (EPI == 0) {
          Cb[idx] = (__bf16)acc[i][j][r];
        } else if (EPI == 1) {
          Cf[idx] = Res[idx] + acc[i][j][r];
        } else {
          float g = (float)Cb[idx];
          Cb[idx] = (__bf16)(g / (1.0f + __expf(-g)) * acc[i][j][r]);
        }
      }
}

// ---------------- rope: out = rot_half(x) * (pm0+pm1) ----------------
__global__ __launch_bounds__(256)
void rope_kernel(const __bf16* __restrict__ qkv, const float* __restrict__ pm,
                 __bf16* __restrict__ qo, __bf16* __restrict__ ko) {
  const int row = blockIdx.x, t = threadIdx.x;
  const int s = row & 2047;
  const __bf16* q = qkv + (size_t)row * QKVN;
  const float* p0 = pm + (size_t)s * DD;
  const float* p1 = p0 + (size_t)2048 * DD;
  __bf16* qr = qo + (size_t)row * DD;
#pragma unroll
  for (int jj = 0; jj < 8; jj++) {
    int i = t + jj * 256;
    float rot = (i < 1024) ? -(float)q[i + 1024] : (float)q[i - 1024];
    qr[i] = (__bf16)(rot * (p0[i] + p1[i]));
  }
  const __bf16* k = q + 2048;
  __bf16* kr = ko + (size_t)row * KVD;
  {
    int i = t;
    float rot = (i < 128) ? -(float)k[i + 128] : (float)k[i - 128];
    kr[i] = (__bf16)(rot * (p0[i] + p1[i]));
  }
}

// ---------------- attention v2: transposed-S flash ----------------
// S^T = K·Q^T (C-layout: lane=q-col, rows=k_t) -> exp in-register is directly
// the A-fragment (k-permuted) of the PV 16x16x32 MFMA. No P through LDS.
// softmax = e/(sum e + 1): no max-rescale needed. grid (S/128, H, B).
__global__ __launch_bounds__(256)
void attn_kernel(const __bf16* __restrict__ Q, const __bf16* __restrict__ Kb,
                 const __bf16* __restrict__ QKV, __bf16* __restrict__ O) {
  __shared__ __align__(16) __bf16 sQ[128 * 72];
  __shared__ __align__(16) __bf16 sK[64 * 72];
  __shared__ __align__(16) __bf16 sV[64 * 72];   // [d][k] (V^T)
  __shared__ float sDen[128];
  const int t = threadIdx.x, l = t & 63, w = t >> 6;
  const int lm = l & 15, lq = l >> 4;
  const int q0 = blockIdx.x * 128;
  const int h = blockIdx.y, b = blockIdx.z;
  const int p = h & 3;                 // kv slice: head h uses dims p*64..p*64+64
  const float scale = 1.0f / (16.0f + 1e-6f);
  {
    const int qr = t >> 3, qc = (t & 7) * 8;
#pragma unroll
    for (int it = 0; it < 4; it++) {
      size_t base = ((size_t)(b * 2048 + q0 + qr + it * 32)) * DD + h * 64 + qc;
      *(uint4*)&sQ[(qr + it * 32) * 72 + qc] = *(const uint4*)(Q + base);
    }
  }
  f32x4 oacc[2][4] = {};                 // [q_j][d_n]
  float dsum[2] = {0.f, 0.f};            // per-lane partial denom, q = q_j*16+lm
  const int ksr = t >> 2, ksc = (t & 3) * 16;
  for (int kt = 0; kt < 2048; kt += 64) {
    const __bf16* krow = Kb + ((size_t)(b * 2048 + kt + ksr)) * KVD + p * 64 + ksc;
    uint4 kv0 = *(const uint4*)(krow);
    uint4 kv1 = *(const uint4*)(krow + 8);
    // V column-mode: lane = d (coalesced), wave w covers k = w*16..+15
    unsigned int vpack[8];
    {
      const __bf16* vbase = QKV + ((size_t)(b * 2048 + kt + w * 16)) * QKVN + 2304 + p * 64 + l;
#pragma unroll
      for (int j2 = 0; j2 < 8; j2++) {
        unsigned int u0 = *(const unsigned short*)(vbase + (size_t)(2 * j2) * QKVN);
        unsigned int u1 = *(const unsigned short*)(vbase + (size_t)(2 * j2 + 1) * QKVN);
        vpack[j2] = u0 | (u1 << 16);
      }
    }
    __syncthreads();
    *(uint4*)&sK[ksr * 72 + ksc] = kv0;
    *(uint4*)&sK[ksr * 72 + ksc + 8] = kv1;
    *(uint4*)&sV[l * 72 + w * 16] = *(uint4*)&vpack[0];
    *(uint4*)&sV[l * 72 + w * 16 + 8] = *(uint4*)&vpack[4];
    __syncthreads();
    // Q fragments (B-operand of S^T mfma), shared across kt chunks
    bf16x8 bQ[2][2];
#pragma unroll
    for (int q_j = 0; q_j < 2; q_j++)
#pragma unroll
      for (int kk = 0; kk < 2; kk++)
        bQ[q_j][kk] = *(const bf16x8*)&sQ[(w * 32 + q_j * 16 + lm) * 72 + kk * 32 + lq * 8];
#pragma unroll
    for (int kt2 = 0; kt2 < 2; kt2++) {  // pairs of 16-row k_t chunks
      union { bf16x8 v; __bf16 e[8]; } pA[2];
#pragma unroll
      for (int c = 0; c < 2; c++) {
        const int kt_i = kt2 * 2 + c;
        f32x4 sacc[2] = {};
#pragma unroll
        for (int kk = 0; kk < 2; kk++) {
          bf16x8 aK = *(const bf16x8*)&sK[(kt_i * 16 + lm) * 72 + kk * 32 + lq * 8];
#pragma unroll
          for (int q_j = 0; q_j < 2; q_j++)
            sacc[q_j] = __builtin_amdgcn_mfma_f32_16x16x32_bf16(aK, bQ[q_j][kk], sacc[q_j], 0, 0, 0);
        }
#pragma unroll
        for (int q_j = 0; q_j < 2; q_j++)
#pragma unroll
          for (int r = 0; r < 4; r++) {
            float e = __expf(sacc[q_j][r] * scale);
            dsum[q_j] += e;
            pA[q_j].e[c * 4 + r] = (__bf16)e;
          }
      }
      // PV: B-frag k-permuted to match pA: j 0..3 <- k=kt2*32+lq*4+j, j 4..7 <- +16
#pragma unroll
      for (int d_n = 0; d_n < 4; d_n++) {
        union { bf16x8 v; bf16x4 h[2]; } bV;
        const __bf16* vb = &sV[(d_n * 16 + lm) * 72 + kt2 * 32 + lq * 4];
        bV.h[0] = *(const bf16x4*)(vb);
        bV.h[1] = *(const bf16x4*)(vb + 16);
#pragma unroll
        for (int q_j = 0; q_j < 2; q_j++)
          oacc[q_j][d_n] = __builtin_amdgcn_mfma_f32_16x16x32_bf16(pA[q_j].v, bV.v, oacc[q_j][d_n], 0, 0, 0);
      }
    }
  }
  // denom: reduce over lq groups (lanes lm, lm+16, lm+32, lm+48 share q)
#pragma unroll
  for (int q_j = 0; q_j < 2; q_j++) {
    dsum[q_j] += __shfl_xor(dsum[q_j], 16, 64);
    dsum[q_j] += __shfl_xor(dsum[q_j], 32, 64);
  }
  if (l < 16) {
    sDen[w * 32 + l] = dsum[0];
    sDen[w * 32 + 16 + l] = dsum[1];
  }
  __syncthreads();
#pragma unroll
  for (int q_j = 0; q_j < 2; q_j++)
#pragma unroll
    for (int d_n = 0; d_n < 4; d_n++)
#pragma unroll
      for (int r = 0; r < 4; r++) {
        int rloc = w * 32 + q_j * 16 + lq * 4 + r;
        int row = q0 + rloc;
        int col = h * 64 + d_n * 16 + lm;
        O[((size_t)(b * 2048 + row)) * DD + col] = (__bf16)(oacc[q_j][d_n][r] / (sDen[rloc] + 1.0f));
      }
}

// ---------------------------------------------------------------------------
extern "C" void kernel_launch(void* const* d_in, const int* in_sizes, int n_in,
                              void* d_out, int out_size, void* d_ws, size_t ws_size,
                              hipStream_t stream) {
  if (ws_size < WS_NEED) return;

  const float* x    = (const float*)d_in[0];
  const float* pm   = (const float*)d_in[1];
  const float* w_na = (const float*)d_in[2];
  const float* w_nf = (const float*)d_in[3];
  const float* wq   = (const float*)d_in[4];
  const float* wk   = (const float*)d_in[5];
  const float* wv   = (const float*)d_in[6];
  const float* wo   = (const float*)d_in[7];
  const float* wg   = (const float*)d_in[8];
  const float* wu   = (const float*)d_in[9];
  const float* wd   = (const float*)d_in[10];

  char* ws = (char*)d_ws;
  __bf16* wqkv_b = (__bf16*)(ws + OFF_WQKV);
  __bf16* wo_b   = (__bf16*)(ws + OFF_WO);
  __bf16* wg_b   = (__bf16*)(ws + OFF_WG);
  __bf16* wu_b   = (__bf16*)(ws + OFF_WU);
  __bf16* wdn_b  = (__bf16*)(ws + OFF_WDN);
  __bf16* h_b    = (__bf16*)(ws + OFF_H);
  __bf16* qkv_b  = (__bf16*)(ws + OFF_QKV);
  __bf16* q_b    = (__bf16*)(ws + OFF_Q);
  __bf16* k_b    = (__bf16*)(ws + OFF_K);
  __bf16* act_b  = (__bf16*)(ws + OFF_ACT);
  float*  x1     = (float*)d_out;

  cvt_kernel<<<4096, 256, 0, stream>>>(wq, wqkv_b, 1048576);
  cvt_kernel<<<512, 256, 0, stream>>>(wk, wqkv_b + (size_t)2048 * 2048, 131072);
  cvt_kernel<<<512, 256, 0, stream>>>(wv, wqkv_b + (size_t)2304 * 2048, 131072);
  cvt_kernel<<<4096, 256, 0, stream>>>(wo, wo_b, 1048576);
  cvt_kernel<<<11264, 256, 0, stream>>>(wg, wg_b, 2883584);
  cvt_kernel<<<11264, 256, 0, stream>>>(wu, wu_b, 2883584);
  cvt_kernel<<<11264, 256, 0, stream>>>(wd, wdn_b, 2883584);

  // ---- attention sublayer ----
  rmsnorm_kernel<<<4096, 256, 0, stream>>>(x, w_na, h_b);
  gemm_nt_kernel<0><<<dim3(20, 32), 256, 0, stream>>>(h_b, wqkv_b, qkv_b, nullptr, nullptr,
                                                      RR, QKVN, DD);
  rope_kernel<<<4096, 256, 0, stream>>>(qkv_b, pm, q_b, k_b);
  attn_kernel<<<dim3(16, 32, 2), 256, 0, stream>>>(q_b, k_b, qkv_b, h_b);
  gemm_nt_kernel<1><<<dim3(16, 32), 256, 0, stream>>>(h_b, wo_b, nullptr, x, x1,
                                                      RR, DD, DD);
  // ---- feedforward sublayer ----
  rmsnorm_kernel<<<4096, 256, 0, stream>>>(x1, w_nf, q_b);
  gemm_nt_kernel<0><<<dim3(44, 32), 256, 0, stream>>>(q_b, wg_b, act_b, nullptr, nullptr,
                                                      RR, DFF, DD);
  gemm_nt_kernel<2><<<dim3(44, 32), 256, 0, stream>>>(q_b, wu_b, act_b, nullptr, nullptr,
                                                      RR, DFF, DD);
  gemm_nt_kernel<1><<<dim3(16, 32), 256, 0, stream>>>(act_b, wdn_b, nullptr, x1, x1,
                                                      RR, DD, DFF);
}